// Round 6
// baseline (130.350 us; speedup 1.0000x reference)
//
#include <hip/hip_runtime.h>
#include <stdint.h>

typedef unsigned short u16;
typedef __attribute__((ext_vector_type(8))) short short8;
typedef __attribute__((ext_vector_type(4))) float f32x4;

#define NB    16
#define DIM   256
#define NTOK  1024

__device__ __forceinline__ u16 f2b(float f) {
    union { float f; uint32_t u; } v; v.f = f;
    uint32_t u = v.u;
    u += 0x7fffu + ((u >> 16) & 1u);
    return (u16)(u >> 16);
}
__device__ __forceinline__ uint32_t pack2(float a, float b) {
    return (uint32_t)f2b(a) | ((uint32_t)f2b(b) << 16);
}
__device__ __forceinline__ f32x4 mfma16(short8 a, short8 b, f32x4 c) {
    return __builtin_amdgcn_mfma_f32_16x16x32_bf16(a, b, c, 0, 0, 0);
}
__device__ __forceinline__ short8 ld8(const u16* p) {
    return *reinterpret_cast<const short8*>(p);
}
__device__ __forceinline__ void gl_lds(const u16* g, u16* l) {
    __builtin_amdgcn_global_load_lds((const __attribute__((address_space(1))) void*)g,
                                     (__attribute__((address_space(3))) void*)l, 16, 0, 0);
}

// ---------------- Kernel 1: pack x -> xbf (bf16 copy, [C][N]) + nodes (bf16 transpose, [N][C])
__global__ __launch_bounds__(256) void pack_kernel(const float* __restrict__ x,
                                                   u16* __restrict__ xbf,
                                                   u16* __restrict__ nodes) {
    __shared__ float tile[64][65];
    int tid = threadIdx.x;
    int blk = blockIdx.x;          // 1024 blocks
    int b  = blk >> 6;
    int t  = blk & 63;
    int c0 = (t >> 4) << 6;        // 0,64,128,192
    int n0 = (t & 15) << 6;        // 0..960
    const float* xb = x + (size_t)b * (DIM * NTOK);
    u16* xbb = xbf + (size_t)b * (DIM * NTOK);
#pragma unroll
    for (int i = 0; i < 16; i++) {
        int idx = i * 256 + tid;
        int cl = idx >> 6, nl = idx & 63;
        float f = xb[(c0 + cl) * NTOK + n0 + nl];
        tile[cl][nl] = f;
        xbb[(c0 + cl) * NTOK + n0 + nl] = f2b(f);
    }
    __syncthreads();
#pragma unroll
    for (int i = 0; i < 16; i++) {
        int idx = i * 256 + tid;
        int nl = idx >> 6, cl = idx & 63;
        nodes[(size_t)(b * NTOK + n0 + nl) * DIM + c0 + cl] = f2b(tile[cl][nl]);
    }
}

// ---------------- Kernel 2: convert 3 weight matrices to bf16 (proj_w, w1, w2)
__global__ __launch_bounds__(256) void wconv_kernel(const float* __restrict__ a,
                                                    const float* __restrict__ b,
                                                    const float* __restrict__ c,
                                                    u16* __restrict__ o) {
    int i = blockIdx.x * 256 + threadIdx.x;  // 0..196607
    const float* s = (i < 65536) ? a : (i < 131072) ? b : c;
    o[i] = f2b(s[i & 65535]);
}

// ---------------- Kernel 3: q = nodes @ proj_w^T + proj_b  (bf16 out, [N][C])
__global__ __launch_bounds__(256) void proj_kernel(const u16* __restrict__ nodes,
                                                   const u16* __restrict__ wbf,
                                                   const float* __restrict__ pb,
                                                   u16* __restrict__ qb) {
    int lane = threadIdx.x & 63;
    int w = threadIdx.x >> 6;
    int lo = lane & 15, hi = lane >> 4;
    int ch = blockIdx.x & 1;               // column half
    int row0 = (blockIdx.x >> 1) * 64 + w * 16;
    const u16* arow = nodes + (size_t)(row0 + lo) * DIM + hi * 8;
    f32x4 acc[8];
#pragma unroll
    for (int i = 0; i < 8; i++) acc[i] = (f32x4){0.f, 0.f, 0.f, 0.f};
#pragma unroll
    for (int t = 0; t < 8; t++) {
        short8 a = ld8(arow + t * 32);
#pragma unroll
        for (int nf = 0; nf < 8; nf++) {
            short8 bfr = ld8(wbf + ((ch * 8 + nf) * 16 + lo) * DIM + t * 32 + hi * 8);
            acc[nf] = mfma16(a, bfr, acc[nf]);
        }
    }
#pragma unroll
    for (int nf = 0; nf < 8; nf++) {
        int col = (ch * 8 + nf) * 16 + lo;
        float bias = pb[col];
#pragma unroll
        for (int r = 0; r < 4; r++) {
            int row = row0 + hi * 4 + r;
            qb[(size_t)row * DIM + col] = f2b(acc[nf][r] + bias);
        }
    }
}

// ---------------- Kernel 4: flash attention, ring-4 pipelined LDS KV staging.
// 256 blocks = 16 q-blocks x 16 batches; 4 waves x 16 q-rows. KV in 32-row
// tiles staged 3 ahead (counted vmcnt(16), raw s_barrier - never drain to 0
// in the main loop, T3+T4). K swizzle: slot^=(row&7); V swizzle: slot^=(ch>>2)&3.
__global__ __launch_bounds__(256) void attn_kernel(const u16* __restrict__ qb,
                                                   const u16* __restrict__ xbf,
                                                   u16* __restrict__ agg) {
    __shared__ u16 kls[4][32 * 256];   // 4 x 16 KB
    __shared__ u16 vls[4][256 * 32];   // 4 x 16 KB

    int lane = threadIdx.x & 63;
    int w = threadIdx.x >> 6;            // 0..3
    int lo = lane & 15, hi = lane >> 4;
    int b  = blockIdx.x & 15;            // batch-per-XCD mapping
    int qt = blockIdx.x >> 4;            // 0..15
    int q0 = qt * 64 + w * 16;
    const u16* qbb = qb  + (size_t)b * (NTOK * DIM);
    const u16* xbb = xbf + (size_t)b * (DIM * NTOK);

    // staging source offsets (elements), loop-invariant (rule #21 pre-swizzle)
    int kOff[4], vOff[4], kDst[4], vDst[4];
#pragma unroll
    for (int i = 0; i < 4; i++) {
        int kr = w * 8 + i * 2 + (lane >> 5);
        kOff[i] = kr * DIM + ((lane & 31) ^ (kr & 7)) * 8;
        kDst[i] = (w * 8 + i * 2) * 256;
        int vc = w * 64 + i * 16 + (lane >> 2);
        vOff[i] = vc * NTOK + ((lane & 3) ^ ((vc >> 2) & 3)) * 8;
        vDst[i] = (w * 64 + i * 16) * 32;
    }

    // Q fragments first (oldest vmcnt entries -> drained by first wait)
    short8 bq[8];
#pragma unroll
    for (int t = 0; t < 8; t++)
        bq[t] = ld8(qbb + (size_t)(q0 + lo) * DIM + t * 32 + hi * 8);

    f32x4 acc[16];
#pragma unroll
    for (int i = 0; i < 16; i++) acc[i] = (f32x4){0.f, 0.f, 0.f, 0.f};
    float m = -1e30f, ell = 0.f;
    const float C1 = 0.0625f * 1.44269504f;
    const float THR = 11.5f;

    // prologue: stage tiles 0,1,2
#pragma unroll
    for (int T = 0; T < 3; T++) {
        int base = T * 32;
#pragma unroll
        for (int i = 0; i < 4; i++) {
            gl_lds(qbb + base * DIM + kOff[i], &kls[T][kDst[i]]);
            gl_lds(xbb + base       + vOff[i], &vls[T][vDst[i]]);
        }
    }

    for (int tt = 0; tt < 32; tt++) {
        if (tt <= 29)      asm volatile("s_waitcnt vmcnt(16)" ::: "memory");
        else if (tt == 30) asm volatile("s_waitcnt vmcnt(8)"  ::: "memory");
        else               asm volatile("s_waitcnt vmcnt(0)"  ::: "memory");
        __builtin_amdgcn_s_barrier();
        if (tt + 3 < 32) {
            int base = (tt + 3) * 32;
            int B = (tt + 3) & 3;
#pragma unroll
            for (int i = 0; i < 4; i++) {
                gl_lds(qbb + base * DIM + kOff[i], &kls[B][kDst[i]]);
                gl_lds(xbb + base       + vOff[i], &vls[B][vDst[i]]);
            }
        }
        const u16* kb = &kls[tt & 3][0];
        const u16* vb = &vls[tt & 3][0];

        // QK^T: 2 score frags (kv 0..15, 16..31)
        f32x4 s0 = (f32x4){0.f, 0.f, 0.f, 0.f};
        f32x4 s1 = (f32x4){0.f, 0.f, 0.f, 0.f};
        __builtin_amdgcn_s_setprio(1);
#pragma unroll
        for (int t = 0; t < 8; t++) {
            int sl = ((t * 4 + hi) ^ (lo & 7)) * 8;
            s0 = mfma16(ld8(kb + lo * 256 + sl),        bq[t], s0);
            s1 = mfma16(ld8(kb + (16 + lo) * 256 + sl), bq[t], s1);
        }
        __builtin_amdgcn_s_setprio(0);

        float p0[4], p1[4];
        float pm = -1e30f;
#pragma unroll
        for (int r = 0; r < 4; r++) {
            p0[r] = s0[r] * C1;
            p1[r] = s1[r] * C1;
            pm = fmaxf(pm, fmaxf(p0[r], p1[r]));
        }
        pm = fmaxf(pm, __shfl_xor(pm, 16));
        pm = fmaxf(pm, __shfl_xor(pm, 32));
        if (!__all(pm <= m + THR)) {
            float mnew = fmaxf(m, pm);
            float sc = exp2f(m - mnew);
            ell *= sc;
#pragma unroll
            for (int i = 0; i < 16; i++) {
                acc[i][0] *= sc; acc[i][1] *= sc; acc[i][2] *= sc; acc[i][3] *= sc;
            }
            m = mnew;
        }
        float psum = 0.f;
#pragma unroll
        for (int r = 0; r < 4; r++) {
            p0[r] = exp2f(p0[r] - m);
            p1[r] = exp2f(p1[r] - m);
            psum += p0[r] + p1[r];
        }
        psum += __shfl_xor(psum, 16);
        psum += __shfl_xor(psum, 32);
        ell += psum;

        // redistribute P (lane: P[q=lo][kv=4*hi+r (+16)]) into B-frag layout
        uint32_t pl0 = pack2(p0[0], p0[1]), ph0 = pack2(p0[2], p0[3]);
        uint32_t pl1 = pack2(p1[0], p1[1]), ph1 = pack2(p1[2], p1[3]);
        int srcA = ((hi & 1) << 5) | lo;
        int srcB = srcA + 16;
        uint32_t w0a = __shfl(pl0, srcA), w0b = __shfl(pl1, srcA);
        uint32_t w1a = __shfl(ph0, srcA), w1b = __shfl(ph1, srcA);
        uint32_t w2a = __shfl(pl0, srcB), w2b = __shfl(pl1, srcB);
        uint32_t w3a = __shfl(ph0, srcB), w3b = __shfl(ph1, srcB);
        bool sel = (hi >= 2);
        union { uint32_t u[4]; short8 v; } pu;
        pu.u[0] = sel ? w0b : w0a;
        pu.u[1] = sel ? w1b : w1a;
        pu.u[2] = sel ? w2b : w2a;
        pu.u[3] = sel ? w3b : w3a;
        short8 pfrag = pu.v;

        // PV: acc[mf] += V^T-frag x P-frag (one 32-kv k-step)
        int vsl = (hi ^ ((lo >> 2) & 3)) * 8;
        __builtin_amdgcn_s_setprio(1);
#pragma unroll
        for (int mf = 0; mf < 16; mf++) {
            short8 a = ld8(vb + (mf * 16 + lo) * 32 + vsl);
            acc[mf] = mfma16(a, pfrag, acc[mf]);
        }
        __builtin_amdgcn_s_setprio(0);
    }

    float rinv = 1.f / ell;
#pragma unroll
    for (int mf = 0; mf < 16; mf++) {
        ushort4 st;
        st.x = f2b(acc[mf][0] * rinv);
        st.y = f2b(acc[mf][1] * rinv);
        st.z = f2b(acc[mf][2] * rinv);
        st.w = f2b(acc[mf][3] * rinv);
        *reinterpret_cast<ushort4*>(agg + (size_t)(b * NTOK + q0 + lo) * DIM + mf * 16 + hi * 4) = st;
    }
}

// ---------------- Kernel 5: FFN + residual, 8-wave blocks (4 rowtiles x 2 colhalves).
__global__ __launch_bounds__(512) void ffn_kernel(const u16* __restrict__ agg,
                                                  const u16* __restrict__ wbf,
                                                  const float* __restrict__ b1,
                                                  const float* __restrict__ b2,
                                                  const float* __restrict__ x,
                                                  float* __restrict__ out) {
    __shared__ u16 hl[64][264];
    int lane = threadIdx.x & 63;
    int w = threadIdx.x >> 6;        // 0..7
    int wr = w & 3, wc = w >> 2;
    int lo = lane & 15, hi = lane >> 4;
    int row0 = blockIdx.x * 64;      // 256 blocks
    int rw = row0 + wr * 16;
    const u16* w1b = wbf + 65536;
    const u16* w2b = wbf + 131072;

    f32x4 acc[8];
#pragma unroll
    for (int i = 0; i < 8; i++) acc[i] = (f32x4){0.f, 0.f, 0.f, 0.f};
    const u16* arow = agg + (size_t)(rw + lo) * DIM + hi * 8;
#pragma unroll
    for (int t = 0; t < 8; t++) {
        short8 a = ld8(arow + t * 32);
#pragma unroll
        for (int nf = 0; nf < 8; nf++) {
            short8 bfr = ld8(w1b + ((wc * 8 + nf) * 16 + lo) * DIM + t * 32 + hi * 8);
            acc[nf] = mfma16(a, bfr, acc[nf]);
        }
    }
#pragma unroll
    for (int nf = 0; nf < 8; nf++) {
        int f = (wc * 8 + nf) * 16 + lo;
        float bias = b1[f];
#pragma unroll
        for (int r = 0; r < 4; r++) {
            float v = acc[nf][r] + bias;
            float g = 0.5f * v * (1.f + erff(v * 0.70710678f));
            hl[wr * 16 + hi * 4 + r][f] = f2b(g);
        }
    }
    __syncthreads();

    f32x4 acc2[8];
#pragma unroll
    for (int i = 0; i < 8; i++) acc2[i] = (f32x4){0.f, 0.f, 0.f, 0.f};
#pragma unroll
    for (int t = 0; t < 8; t++) {
        short8 bh = ld8(&hl[wr * 16 + lo][t * 32 + hi * 8]);
#pragma unroll
        for (int mf = 0; mf < 8; mf++) {
            short8 a = ld8(w2b + ((wc * 8 + mf) * 16 + lo) * DIM + t * 32 + hi * 8);
            acc2[mf] = mfma16(a, bh, acc2[mf]);
        }
    }
    int bidx = row0 >> 10;
    int n = (rw & 1023) + lo;
#pragma unroll
    for (int mf = 0; mf < 8; mf++) {
#pragma unroll
        for (int r = 0; r < 4; r++) {
            int co = (wc * 8 + mf) * 16 + hi * 4 + r;
            size_t addr = (size_t)bidx * (DIM * NTOK) + (size_t)co * NTOK + n;
            out[addr] = acc2[mf][r] + b2[co] + x[addr];
        }
    }
}

extern "C" void kernel_launch(void* const* d_in, const int* in_sizes, int n_in,
                              void* d_out, int out_size, void* d_ws, size_t ws_size,
                              hipStream_t stream) {
    const float* x      = (const float*)d_in[0];
    const float* proj_w = (const float*)d_in[1];
    const float* proj_b = (const float*)d_in[2];
    const float* w1     = (const float*)d_in[3];
    const float* b1     = (const float*)d_in[4];
    const float* w2     = (const float*)d_in[5];
    const float* b2     = (const float*)d_in[6];
    float* out = (float*)d_out;

    u16* xbf   = (u16*)d_ws;                 // 16*256*1024 = 4,194,304 elems
    u16* nodes = xbf   + 4194304;
    u16* qb    = nodes + 4194304;
    u16* agg   = qb    + 4194304;
    u16* wbf   = agg   + 4194304;            // 3*65536 elems

    pack_kernel <<<1024, 256, 0, stream>>>(x, xbf, nodes);
    wconv_kernel<<<768,  256, 0, stream>>>(proj_w, w1, w2, wbf);
    proj_kernel <<<512,  256, 0, stream>>>(nodes, wbf, proj_b, qb);
    attn_kernel <<<256,  256, 0, stream>>>(qb, xbf, agg);
    ffn_kernel  <<<256,  512, 0, stream>>>(agg, wbf, b1, b2, x, out);
}

// Round 7
// 126.392 us; speedup vs baseline: 1.0313x; 1.0313x over previous
//
#include <hip/hip_runtime.h>
#include <stdint.h>

typedef unsigned short u16;
typedef __attribute__((ext_vector_type(8))) short short8;
typedef __attribute__((ext_vector_type(4))) float f32x4;

#define NB    16
#define DIM   256
#define NTOK  1024

__device__ __forceinline__ u16 f2b(float f) {
    union { float f; uint32_t u; } v; v.f = f;
    uint32_t u = v.u;
    u += 0x7fffu + ((u >> 16) & 1u);
    return (u16)(u >> 16);
}
__device__ __forceinline__ uint32_t pack2(float a, float b) {
    return (uint32_t)f2b(a) | ((uint32_t)f2b(b) << 16);
}
__device__ __forceinline__ f32x4 mfma16(short8 a, short8 b, f32x4 c) {
    return __builtin_amdgcn_mfma_f32_16x16x32_bf16(a, b, c, 0, 0, 0);
}
__device__ __forceinline__ short8 ld8(const u16* p) {
    return *reinterpret_cast<const short8*>(p);
}
__device__ __forceinline__ void gl_lds(const u16* g, u16* l) {
    __builtin_amdgcn_global_load_lds((const __attribute__((address_space(1))) void*)g,
                                     (__attribute__((address_space(3))) void*)l, 16, 0, 0);
}

// ---------------- Kernel 1: pack x -> xbf (bf16, [C][N]) + nodes (bf16 transpose, [N][C])
// vectorized: float4 loads, ushort4 stores, LDS transpose (pad 67 words: 2-way free)
__global__ __launch_bounds__(256) void pack_kernel(const float* __restrict__ x,
                                                   u16* __restrict__ xbf,
                                                   u16* __restrict__ nodes) {
    __shared__ float tile[64][67];
    int tid = threadIdx.x;
    int blk = blockIdx.x;          // 1024 blocks
    int b  = blk >> 6;
    int t  = blk & 63;
    int c0 = (t >> 4) << 6;        // 0,64,128,192
    int n0 = (t & 15) << 6;        // 0..960
    const float* xb = x + (size_t)b * (DIM * NTOK);
    u16* xbb = xbf + (size_t)b * (DIM * NTOK);
#pragma unroll
    for (int i = 0; i < 4; i++) {
        int idx = i * 256 + tid;           // 0..1023
        int cl = idx >> 4, nq = idx & 15;
        float4 f = *reinterpret_cast<const float4*>(xb + (size_t)(c0 + cl) * NTOK + n0 + nq * 4);
        tile[cl][nq * 4 + 0] = f.x;
        tile[cl][nq * 4 + 1] = f.y;
        tile[cl][nq * 4 + 2] = f.z;
        tile[cl][nq * 4 + 3] = f.w;
        ushort4 s;
        s.x = f2b(f.x); s.y = f2b(f.y); s.z = f2b(f.z); s.w = f2b(f.w);
        *reinterpret_cast<ushort4*>(xbb + (size_t)(c0 + cl) * NTOK + n0 + nq * 4) = s;
    }
    __syncthreads();
#pragma unroll
    for (int i = 0; i < 4; i++) {
        int idx = i * 256 + tid;
        int nl = idx >> 4, cq = idx & 15;
        ushort4 s;
        s.x = f2b(tile[cq * 4 + 0][nl]);
        s.y = f2b(tile[cq * 4 + 1][nl]);
        s.z = f2b(tile[cq * 4 + 2][nl]);
        s.w = f2b(tile[cq * 4 + 3][nl]);
        *reinterpret_cast<ushort4*>(nodes + (size_t)(b * NTOK + n0 + nl) * DIM + c0 + cq * 4) = s;
    }
}

// ---------------- Kernel 2: convert 3 weight matrices to bf16 (proj_w, w1, w2)
__global__ __launch_bounds__(256) void wconv_kernel(const float* __restrict__ a,
                                                    const float* __restrict__ b,
                                                    const float* __restrict__ c,
                                                    u16* __restrict__ o) {
    int i = blockIdx.x * 256 + threadIdx.x;  // 0..196607
    const float* s = (i < 65536) ? a : (i < 131072) ? b : c;
    o[i] = f2b(s[i & 65535]);
}

// ---------------- Kernel 3: q = nodes @ proj_w^T + proj_b  (bf16 out, [N][C])
__global__ __launch_bounds__(256) void proj_kernel(const u16* __restrict__ nodes,
                                                   const u16* __restrict__ wbf,
                                                   const float* __restrict__ pb,
                                                   u16* __restrict__ qb) {
    int lane = threadIdx.x & 63;
    int w = threadIdx.x >> 6;
    int lo = lane & 15, hi = lane >> 4;
    int ch = blockIdx.x & 1;               // column half
    int row0 = (blockIdx.x >> 1) * 64 + w * 16;
    const u16* arow = nodes + (size_t)(row0 + lo) * DIM + hi * 8;
    f32x4 acc[8];
#pragma unroll
    for (int i = 0; i < 8; i++) acc[i] = (f32x4){0.f, 0.f, 0.f, 0.f};
#pragma unroll
    for (int t = 0; t < 8; t++) {
        short8 a = ld8(arow + t * 32);
#pragma unroll
        for (int nf = 0; nf < 8; nf++) {
            short8 bfr = ld8(wbf + ((ch * 8 + nf) * 16 + lo) * DIM + t * 32 + hi * 8);
            acc[nf] = mfma16(a, bfr, acc[nf]);
        }
    }
#pragma unroll
    for (int nf = 0; nf < 8; nf++) {
        int col = (ch * 8 + nf) * 16 + lo;
        float bias = pb[col];
#pragma unroll
        for (int r = 0; r < 4; r++) {
            int row = row0 + hi * 4 + r;
            qb[(size_t)row * DIM + col] = f2b(acc[nf][r] + bias);
        }
    }
}

// ---------------- Kernel 4: flash attention, 64KB LDS -> 2 blocks/CU.
// 256 blocks = 16 q-blocks x 16 batches; 4 waves x 16 q-rows. KV in 32-row
// tiles, double-buffered (2 x (16KB K + 16KB V)). Simple schedule:
// {stage(t+1) -> compute(t) -> __syncthreads} ; cross-block TLP hides drains.
// K swizzle: slot(5b) ^= row&7. V swizzle: slot(2b) ^= chan&3.
__global__ __launch_bounds__(256) void attn_kernel(const u16* __restrict__ qb,
                                                   const u16* __restrict__ xbf,
                                                   u16* __restrict__ agg) {
    __shared__ u16 kls[2][32 * 256];   // 2 x 16 KB
    __shared__ u16 vls[2][256 * 32];   // 2 x 16 KB

    int lane = threadIdx.x & 63;
    int w = threadIdx.x >> 6;            // 0..3
    int lo = lane & 15, hi = lane >> 4;
    int b  = blockIdx.x & 15;            // batch-per-XCD mapping (XCD = b%8)
    int qt = blockIdx.x >> 4;            // 0..15
    int q0 = qt * 64 + w * 16;
    const u16* qbb = qb  + (size_t)b * (NTOK * DIM);
    const u16* xbb = xbf + (size_t)b * (DIM * NTOK);

    // staging source offsets (elements), loop-invariant (pre-swizzled source, rule #21)
    int kOff[4], vOff[4], kDst[4], vDst[4];
#pragma unroll
    for (int i = 0; i < 4; i++) {
        int kr = w * 8 + i * 2 + (lane >> 5);                 // K row in tile (2 rows/instr)
        kOff[i] = kr * DIM + ((lane & 31) ^ (kr & 7)) * 8;
        kDst[i] = (w * 8 + i * 2) * 256;
        int vc = w * 64 + i * 16 + (lane >> 2);               // V channel (16 ch/instr)
        vOff[i] = vc * NTOK + ((lane & 3) ^ (vc & 3)) * 8;
        vDst[i] = (w * 64 + i * 16) * 32;
    }

    short8 bq[8];
#pragma unroll
    for (int t = 0; t < 8; t++)
        bq[t] = ld8(qbb + (size_t)(q0 + lo) * DIM + t * 32 + hi * 8);

    f32x4 acc[16];
#pragma unroll
    for (int i = 0; i < 16; i++) acc[i] = (f32x4){0.f, 0.f, 0.f, 0.f};
    float m = -1e30f, ell = 0.f;
    const float C1 = 0.0625f * 1.44269504f;
    const float THR = 11.5f;

    // prologue: stage tile 0 into buf 0
#pragma unroll
    for (int i = 0; i < 4; i++) {
        gl_lds(qbb + kOff[i], &kls[0][kDst[i]]);
        gl_lds(xbb + vOff[i], &vls[0][vDst[i]]);
    }
    __syncthreads();

    for (int tt = 0; tt < 32; tt++) {
        int buf = tt & 1;
        if (tt < 31) {
            int base = (tt + 1) * 32;
#pragma unroll
            for (int i = 0; i < 4; i++) {
                gl_lds(qbb + base * DIM + kOff[i], &kls[buf ^ 1][kDst[i]]);
                gl_lds(xbb + base       + vOff[i], &vls[buf ^ 1][vDst[i]]);
            }
        }
        const u16* kb = &kls[buf][0];
        const u16* vb = &vls[buf][0];

        // QK^T: 2 score frags (kv 0..15, 16..31)
        f32x4 s0 = (f32x4){0.f, 0.f, 0.f, 0.f};
        f32x4 s1 = (f32x4){0.f, 0.f, 0.f, 0.f};
        __builtin_amdgcn_s_setprio(1);
#pragma unroll
        for (int t = 0; t < 8; t++) {
            int sl = ((t * 4 + hi) ^ (lo & 7)) * 8;
            s0 = mfma16(ld8(kb + lo * 256 + sl),        bq[t], s0);
            s1 = mfma16(ld8(kb + (16 + lo) * 256 + sl), bq[t], s1);
        }
        __builtin_amdgcn_s_setprio(0);

        float p0[4], p1[4];
        float pm = -1e30f;
#pragma unroll
        for (int r = 0; r < 4; r++) {
            p0[r] = s0[r] * C1;
            p1[r] = s1[r] * C1;
            pm = fmaxf(pm, fmaxf(p0[r], p1[r]));
        }
        pm = fmaxf(pm, __shfl_xor(pm, 16));
        pm = fmaxf(pm, __shfl_xor(pm, 32));
        if (!__all(pm <= m + THR)) {
            float mnew = fmaxf(m, pm);
            float sc = exp2f(m - mnew);
            ell *= sc;
#pragma unroll
            for (int i = 0; i < 16; i++) {
                acc[i][0] *= sc; acc[i][1] *= sc; acc[i][2] *= sc; acc[i][3] *= sc;
            }
            m = mnew;
        }
        float psum = 0.f;
#pragma unroll
        for (int r = 0; r < 4; r++) {
            p0[r] = exp2f(p0[r] - m);
            p1[r] = exp2f(p1[r] - m);
            psum += p0[r] + p1[r];
        }
        psum += __shfl_xor(psum, 16);
        psum += __shfl_xor(psum, 32);
        ell += psum;

        // redistribute P (lane: P[q=lo][kv=4*hi+r (+16)]) into B-frag layout
        uint32_t pl0 = pack2(p0[0], p0[1]), ph0 = pack2(p0[2], p0[3]);
        uint32_t pl1 = pack2(p1[0], p1[1]), ph1 = pack2(p1[2], p1[3]);
        int srcA = ((hi & 1) << 5) | lo;
        int srcB = srcA + 16;
        uint32_t w0a = __shfl(pl0, srcA), w0b = __shfl(pl1, srcA);
        uint32_t w1a = __shfl(ph0, srcA), w1b = __shfl(ph1, srcA);
        uint32_t w2a = __shfl(pl0, srcB), w2b = __shfl(pl1, srcB);
        uint32_t w3a = __shfl(ph0, srcB), w3b = __shfl(ph1, srcB);
        bool sel = (hi >= 2);
        union { uint32_t u[4]; short8 v; } pu;
        pu.u[0] = sel ? w0b : w0a;
        pu.u[1] = sel ? w1b : w1a;
        pu.u[2] = sel ? w2b : w2a;
        pu.u[3] = sel ? w3b : w3a;
        short8 pfrag = pu.v;

        // PV: acc[mf] += V^T-frag x P-frag (one 32-kv k-step)
        int vsl = (hi ^ (lo & 3)) * 8;
        __builtin_amdgcn_s_setprio(1);
#pragma unroll
        for (int mf = 0; mf < 16; mf++) {
            short8 a = ld8(vb + (mf * 16 + lo) * 32 + vsl);
            acc[mf] = mfma16(a, pfrag, acc[mf]);
        }
        __builtin_amdgcn_s_setprio(0);
        __syncthreads();
    }

    float rinv = 1.f / ell;
#pragma unroll
    for (int mf = 0; mf < 16; mf++) {
        ushort4 st;
        st.x = f2b(acc[mf][0] * rinv);
        st.y = f2b(acc[mf][1] * rinv);
        st.z = f2b(acc[mf][2] * rinv);
        st.w = f2b(acc[mf][3] * rinv);
        *reinterpret_cast<ushort4*>(agg + (size_t)(b * NTOK + q0 + lo) * DIM + mf * 16 + hi * 4) = st;
    }
}

// ---------------- Kernel 5: FFN + residual, 8-wave blocks (4 rowtiles x 2 colhalves).
__global__ __launch_bounds__(512) void ffn_kernel(const u16* __restrict__ agg,
                                                  const u16* __restrict__ wbf,
                                                  const float* __restrict__ b1,
                                                  const float* __restrict__ b2,
                                                  const float* __restrict__ x,
                                                  float* __restrict__ out) {
    __shared__ u16 hl[64][264];
    int lane = threadIdx.x & 63;
    int w = threadIdx.x >> 6;        // 0..7
    int wr = w & 3, wc = w >> 2;
    int lo = lane & 15, hi = lane >> 4;
    int row0 = blockIdx.x * 64;      // 256 blocks
    int rw = row0 + wr * 16;
    const u16* w1b = wbf + 65536;
    const u16* w2b = wbf + 131072;

    f32x4 acc[8];
#pragma unroll
    for (int i = 0; i < 8; i++) acc[i] = (f32x4){0.f, 0.f, 0.f, 0.f};
    const u16* arow = agg + (size_t)(rw + lo) * DIM + hi * 8;
#pragma unroll
    for (int t = 0; t < 8; t++) {
        short8 a = ld8(arow + t * 32);
#pragma unroll
        for (int nf = 0; nf < 8; nf++) {
            short8 bfr = ld8(w1b + ((wc * 8 + nf) * 16 + lo) * DIM + t * 32 + hi * 8);
            acc[nf] = mfma16(a, bfr, acc[nf]);
        }
    }
#pragma unroll
    for (int nf = 0; nf < 8; nf++) {
        int f = (wc * 8 + nf) * 16 + lo;
        float bias = b1[f];
#pragma unroll
        for (int r = 0; r < 4; r++) {
            float v = acc[nf][r] + bias;
            float g = 0.5f * v * (1.f + erff(v * 0.70710678f));
            hl[wr * 16 + hi * 4 + r][f] = f2b(g);
        }
    }
    __syncthreads();

    f32x4 acc2[8];
#pragma unroll
    for (int i = 0; i < 8; i++) acc2[i] = (f32x4){0.f, 0.f, 0.f, 0.f};
#pragma unroll
    for (int t = 0; t < 8; t++) {
        short8 bh = ld8(&hl[wr * 16 + lo][t * 32 + hi * 8]);
#pragma unroll
        for (int mf = 0; mf < 8; mf++) {
            short8 a = ld8(w2b + ((wc * 8 + mf) * 16 + lo) * DIM + t * 32 + hi * 8);
            acc2[mf] = mfma16(a, bh, acc2[mf]);
        }
    }
    int bidx = row0 >> 10;
    int n = (rw & 1023) + lo;
#pragma unroll
    for (int mf = 0; mf < 8; mf++) {
#pragma unroll
        for (int r = 0; r < 4; r++) {
            int co = (wc * 8 + mf) * 16 + hi * 4 + r;
            size_t addr = (size_t)bidx * (DIM * NTOK) + (size_t)co * NTOK + n;
            out[addr] = acc2[mf][r] + b2[co] + x[addr];
        }
    }
}

extern "C" void kernel_launch(void* const* d_in, const int* in_sizes, int n_in,
                              void* d_out, int out_size, void* d_ws, size_t ws_size,
                              hipStream_t stream) {
    const float* x      = (const float*)d_in[0];
    const float* proj_w = (const float*)d_in[1];
    const float* proj_b = (const float*)d_in[2];
    const float* w1     = (const float*)d_in[3];
    const float* b1     = (const float*)d_in[4];
    const float* w2     = (const float*)d_in[5];
    const float* b2     = (const float*)d_in[6];
    float* out = (float*)d_out;

    u16* xbf   = (u16*)d_ws;                 // 16*256*1024 = 4,194,304 elems
    u16* nodes = xbf   + 4194304;
    u16* qb    = nodes + 4194304;
    u16* agg   = qb    + 4194304;
    u16* wbf   = agg   + 4194304;            // 3*65536 elems

    pack_kernel <<<1024, 256, 0, stream>>>(x, xbf, nodes);
    wconv_kernel<<<768,  256, 0, stream>>>(proj_w, w1, w2, wbf);
    proj_kernel <<<512,  256, 0, stream>>>(nodes, wbf, proj_b, qb);
    attn_kernel <<<256,  256, 0, stream>>>(qb, xbf, agg);
    ffn_kernel  <<<256,  512, 0, stream>>>(agg, wbf, b1, b2, x, out);
}